// Round 1
// 253.012 us; speedup vs baseline: 1.0243x; 1.0243x over previous
//
#include <hip/hip_runtime.h>
#include <hip/hip_bf16.h>

#define B_SZ 16384
#define F_SZ 2048
#define D_SZ 256
#define E_SZ 8
#define GRID_G 528   // (sum_e ceil(count_e/64) <= 264) * 2 n-tiles

typedef __attribute__((ext_vector_type(8))) short bhalf8;
typedef __attribute__((ext_vector_type(4))) float fl4;

__device__ __forceinline__ short f2b(float f) {
  __hip_bfloat16 h = __float2bfloat16(f);
  union { __hip_bfloat16 h; short s; } u;
  u.h = h;
  return u.s;
}

// ---------------- bucket scatter ----------------
__global__ void k_scatter(const int* __restrict__ ids, int* __restrict__ counts,
                          int* __restrict__ perm) {
  __shared__ int lcnt[E_SZ], lbase[E_SZ];
  int t = threadIdx.x;
  if (t < E_SZ) lcnt[t] = 0;
  __syncthreads();
  int b = blockIdx.x * 256 + t;
  int e = ids[b];
  int p = atomicAdd(&lcnt[e], 1);
  __syncthreads();
  if (t < E_SZ) lbase[t] = atomicAdd(&counts[t], lcnt[t]);
  __syncthreads();
  perm[e * B_SZ + lbase[e] + p] = b;
}

// ---------------- W transpose+cast: Wt[e][d][f] = bf16(W[e][f][d]) ----------------
__global__ void k_transpose(const float* __restrict__ W, __hip_bfloat16* __restrict__ Wt) {
  __shared__ float tile[64][65];
  int e = blockIdx.z;
  int f0 = blockIdx.x * 64;
  int d0 = blockIdx.y * 64;
  int t = threadIdx.x;
  const float* src = W + ((size_t)e * F_SZ + f0) * D_SZ + d0;
  int fr = t >> 2, c0 = t & 3;
#pragma unroll
  for (int c = c0; c < 16; c += 4) {
    float4 v = *(const float4*)(src + (size_t)fr * D_SZ + c * 4);
    tile[fr][c * 4 + 0] = v.x;
    tile[fr][c * 4 + 1] = v.y;
    tile[fr][c * 4 + 2] = v.z;
    tile[fr][c * 4 + 3] = v.w;
  }
  __syncthreads();
  int dr = t >> 2, cc = t & 3;
  union { unsigned short u[16]; bhalf8 v[2]; } pk;
#pragma unroll
  for (int k = 0; k < 16; ++k) pk.u[k] = (unsigned short)f2b(tile[cc * 16 + k][dr]);
  __hip_bfloat16* dst = Wt + ((size_t)e * D_SZ + d0 + dr) * F_SZ + f0 + cc * 16;
  ((bhalf8*)dst)[0] = pk.v[0];
  ((bhalf8*)dst)[1] = pk.v[1];
}

// ---------------- async 16B global -> LDS ----------------
__device__ __forceinline__ void load_lds16(const __hip_bfloat16* g, __hip_bfloat16* l) {
  __builtin_amdgcn_global_load_lds((const __attribute__((address_space(1))) void*)g,
                                   (__attribute__((address_space(3))) void*)l, 16, 0, 0);
}

// ---------------- gather GEMM: BM=64, BN=128, BK=64, pipelined ----------------
// 8 waves (2m x 4n), wave tile 32x32, 8 MFMA/iter/wave.
// Double-buffered As/Bs; B-DMA prefetch distance 1, A-reg prefetch distance 1
// (A(k+2) issued during iter k, stays in flight across the barrier via counted
// vmcnt(2) -- only B(k+1) is drained at the iteration boundary).
// LDS layouts (bf16, row stride 64 elems = 128B) XOR-swizzled: 16B chunk c at
// physical (c ^ (row&7)) -> fragment ds_read_b128 is 2-way aliased (free).
__launch_bounds__(512, 4)
__global__ void k_gemm(const float* __restrict__ x, const __hip_bfloat16* __restrict__ Wt,
                       const float* __restrict__ bias, const int* __restrict__ counts,
                       const int* __restrict__ perm, float* __restrict__ out) {
  // flattened decode: blockIdx.x -> (expert e, mbase, nb)
  int id = blockIdx.x;
  int nb = (id & 1) * 128;
  int mt = id >> 1;
  int e = -1, mbase = 0, count = 0;
  {
    int acc0 = 0;
#pragma unroll
    for (int ee = 0; ee < E_SZ; ++ee) {
      int c = counts[ee];
      int nt = (c + 63) >> 6;
      if (e < 0 && mt < acc0 + nt) { e = ee; mbase = (mt - acc0) * 64; count = c; }
      acc0 += nt;
    }
  }
  if (e < 0) return;

  __shared__ __align__(16) __hip_bfloat16 As[2 * 64 * 64];    // 16 KB (2 bufs)
  __shared__ __align__(16) __hip_bfloat16 Bs[2 * 128 * 64];   // 32 KB (2 bufs)

  int t = threadIdx.x;
  int w = t >> 6;
  int lane = t & 63;
  int wm = w >> 2, wn = w & 3;
  int l15 = lane & 15;
  int q = lane >> 4;

  const int* permE = perm + e * B_SZ;

  // ---- A staging setup: float4 index fi = i*512+t -> row i*32+(t>>4), k=(t&15)*4 ----
  int tr = t >> 4;      // 0..31
  int tc = t & 15;      // float4 index within row
  const float* pA[2];
  int wAo[2];           // As element offset for this thread's ds_write (8B each)
#pragma unroll
  for (int i = 0; i < 2; ++i) {
    int r = i * 32 + tr;
    int gm = mbase + r;
    int src = permE[(gm < count) ? gm : mbase];
    pA[i] = x + (size_t)src * F_SZ + tc * 4;
    int cw = tc >> 1, half = tc & 1;
    wAo[i] = r * 64 + ((cw ^ (r & 7)) * 8) + half * 4;
  }

  // ---- B staging setup: physical chunk p = i*512+t; n=p>>3; logical chunk=(p&7)^(n&7) ----
  const __hip_bfloat16* pB[2];
  int dB[2];            // wave-uniform LDS elem offset (HW adds lane*16B)
#pragma unroll
  for (int i = 0; i < 2; ++i) {
    int p = i * 512 + t;
    int n = p >> 3;
    int cl = (p & 7) ^ (n & 7);
    pB[i] = Wt + (size_t)(e * D_SZ + nb + n) * F_SZ + cl * 8;
    dB[i] = i * 4096 + w * 512;
  }

  // fragment read offsets (element units)
  int rAo[2][2], rBo[2][2];
#pragma unroll
  for (int ks = 0; ks < 2; ++ks) {
#pragma unroll
    for (int i = 0; i < 2; ++i) {
      int m = wm * 32 + i * 16 + l15;
      rAo[ks][i] = m * 64 + (((ks * 4 + q) ^ (m & 7)) * 8);
    }
#pragma unroll
    for (int j = 0; j < 2; ++j) {
      int n = wn * 32 + j * 16 + l15;
      rBo[ks][j] = n * 64 + (((ks * 4 + q) ^ (n & 7)) * 8);
    }
  }

  fl4 zz = {0.0f, 0.0f, 0.0f, 0.0f};
  fl4 acc[2][2];
#pragma unroll
  for (int i = 0; i < 2; ++i)
#pragma unroll
    for (int j = 0; j < 2; ++j) acc[i][j] = zz;

  float4 av[2];

  // ---------------- prologue: B(0)->Bs0, A(0)->As0, A(1) in flight ----------------
#pragma unroll
  for (int i = 0; i < 2; ++i) load_lds16(pB[i], Bs + dB[i]);
  __builtin_amdgcn_sched_barrier(0);
#pragma unroll
  for (int i = 0; i < 2; ++i) av[i] = *(const float4*)(pA[i]);
#pragma unroll
  for (int i = 0; i < 2; ++i) {
    short4 s;
    s.x = f2b(av[i].x); s.y = f2b(av[i].y);
    s.z = f2b(av[i].z); s.w = f2b(av[i].w);
    *(short4*)(As + wAo[i]) = s;
  }
#pragma unroll
  for (int i = 0; i < 2; ++i) av[i] = *(const float4*)(pA[i] + 64);
  __builtin_amdgcn_sched_barrier(0);
  asm volatile("s_waitcnt vmcnt(2) lgkmcnt(0)");
  __builtin_amdgcn_sched_barrier(0);
  __builtin_amdgcn_s_barrier();
  __builtin_amdgcn_sched_barrier(0);

  // ---------------- main loop: iters 0..30 (iter 31 = tail, compute only) ----------------
  for (int k = 0; k < 31; ++k) {
    int cb = (k & 1);
    int nx = cb ^ 1;
    // B(k+1) -> Bs[nx]
#pragma unroll
    for (int i = 0; i < 2; ++i) load_lds16(pB[i] + (k + 1) * 64, Bs + nx * 8192 + dB[i]);
    __builtin_amdgcn_sched_barrier(0);
    // cvt A(k+1) (loaded last iter) -> As[nx]
#pragma unroll
    for (int i = 0; i < 2; ++i) {
      short4 s;
      s.x = f2b(av[i].x); s.y = f2b(av[i].y);
      s.z = f2b(av[i].z); s.w = f2b(av[i].w);
      *(short4*)(As + nx * 4096 + wAo[i]) = s;
    }
    // A(k+2) issue (wrapped at the tail; kept live below so the count holds)
    int kn = (k + 2) & 31;
#pragma unroll
    for (int i = 0; i < 2; ++i) av[i] = *(const float4*)(pA[i] + kn * 64);
    // MFMA on buffer cb
    {
      const __hip_bfloat16* Ab = As + cb * 4096;
      const __hip_bfloat16* Bb = Bs + cb * 8192;
#pragma unroll
      for (int ks = 0; ks < 2; ++ks) {
        bhalf8 af[2], bf[2];
#pragma unroll
        for (int i = 0; i < 2; ++i) af[i] = *(const bhalf8*)(Ab + rAo[ks][i]);
#pragma unroll
        for (int j = 0; j < 2; ++j) bf[j] = *(const bhalf8*)(Bb + rBo[ks][j]);
#pragma unroll
        for (int i = 0; i < 2; ++i)
#pragma unroll
          for (int j = 0; j < 2; ++j)
            acc[i][j] = __builtin_amdgcn_mfma_f32_16x16x32_bf16(af[i], bf[j], acc[i][j], 0, 0, 0);
      }
    }
    // drain B(k+1) only; A(k+2) stays in flight across the barrier
    __builtin_amdgcn_sched_barrier(0);
    asm volatile("s_waitcnt vmcnt(2) lgkmcnt(0)");
    __builtin_amdgcn_sched_barrier(0);
    __builtin_amdgcn_s_barrier();
    __builtin_amdgcn_sched_barrier(0);
  }
  // keep the tail prefetch alive so it is not DCE'd (vmcnt discipline depends on it)
  asm volatile("" :: "v"(av[0].x), "v"(av[1].x));

  // tail iter 31: compute on buffer 1
  {
    const __hip_bfloat16* Ab = As + 4096;
    const __hip_bfloat16* Bb = Bs + 8192;
#pragma unroll
    for (int ks = 0; ks < 2; ++ks) {
      bhalf8 af[2], bf[2];
#pragma unroll
      for (int i = 0; i < 2; ++i) af[i] = *(const bhalf8*)(Ab + rAo[ks][i]);
#pragma unroll
      for (int j = 0; j < 2; ++j) bf[j] = *(const bhalf8*)(Bb + rBo[ks][j]);
#pragma unroll
      for (int i = 0; i < 2; ++i)
#pragma unroll
        for (int j = 0; j < 2; ++j)
          acc[i][j] = __builtin_amdgcn_mfma_f32_16x16x32_bf16(af[i], bf[j], acc[i][j], 0, 0, 0);
    }
  }

  // epilogue: C/D layout col = lane&15, row = q*4 + reg
  float bv[2];
#pragma unroll
  for (int j = 0; j < 2; ++j) bv[j] = bias[e * D_SZ + nb + wn * 32 + j * 16 + l15];

#pragma unroll
  for (int i = 0; i < 2; ++i) {
#pragma unroll
    for (int r = 0; r < 4; ++r) {
      int gm = mbase + wm * 32 + i * 16 + q * 4 + r;
      if (gm < count) {
        int row = permE[gm];
        float* po = out + (size_t)row * D_SZ + nb + wn * 32;
#pragma unroll
        for (int j = 0; j < 2; ++j) po[j * 16 + l15] = acc[i][j][r] + bv[j];
      }
    }
  }
}

extern "C" void kernel_launch(void* const* d_in, const int* in_sizes, int n_in,
                              void* d_out, int out_size, void* d_ws, size_t ws_size,
                              hipStream_t stream) {
  const float* x = (const float*)d_in[0];
  const float* W = (const float*)d_in[1];
  const float* bias = (const float*)d_in[2];
  const int* ids = (const int*)d_in[3];
  float* out = (float*)d_out;

  char* ws = (char*)d_ws;
  int* counts = (int*)ws;                                 // 32 B
  int* perm = (int*)(ws + 256);                           // 512 KB
  __hip_bfloat16* Wt = (__hip_bfloat16*)(ws + (1 << 20)); // 8 MB

  hipMemsetAsync(counts, 0, E_SZ * sizeof(int), stream);
  k_scatter<<<B_SZ / 256, 256, 0, stream>>>(ids, counts, perm);
  k_transpose<<<dim3(F_SZ / 64, D_SZ / 64, E_SZ), 256, 0, stream>>>(W, Wt);
  k_gemm<<<GRID_G, 512, 0, stream>>>(x, Wt, bias, counts, perm, out);
}